// Round 7
// baseline (258.049 us; speedup 1.0000x reference)
//
#include <hip/hip_runtime.h>
#include <cstdint>

typedef __bf16 bf16x8 __attribute__((ext_vector_type(8)));
typedef float  f32x4  __attribute__((ext_vector_type(4)));

// split 8 f32 into hi/lo bf16 fragments (hi+lo ~ 16-bit mantissa)
__device__ __forceinline__ void split8(const float* v, bf16x8& hi, bf16x8& lo) {
    union { bf16x8 v; __bf16 e[8]; } h, l;
    #pragma unroll
    for (int j = 0; j < 8; j++) {
        __bf16 hb = (__bf16)v[j];
        float  r  = v[j] - (float)hb;
        h.e[j] = hb; l.e[j] = (__bf16)r;
    }
    hi = h.v; lo = l.v;
}
__device__ __forceinline__ bf16x8 cvt8(const float* v) {
    union { bf16x8 v; __bf16 e[8]; } u;
    #pragma unroll
    for (int j = 0; j < 8; j++) u.e[j] = (__bf16)v[j];
    return u.v;
}
__device__ __forceinline__ void splitstore(unsigned short* ph, unsigned short* pl, float v) {
    __bf16 hb = (__bf16)v;
    float  r  = v - (float)hb;
    __bf16 lb = (__bf16)r;
    unsigned short hu, lu;
    __builtin_memcpy(&hu, &hb, 2); __builtin_memcpy(&lu, &lb, 2);
    *ph = hu; *pl = lu;
}
__device__ __forceinline__ unsigned short f2bfh(float v) {
    __bf16 hb = (__bf16)v; unsigned short hu;
    __builtin_memcpy(&hu, &hb, 2); return hu;
}

// ---------------- Kzero: zero the atomic-accumulation region (fallback) -------
__global__ __launch_bounds__(256)
void kzero(float4* __restrict__ p) {
    p[blockIdx.x * 256 + threadIdx.x] = float4{0.f, 0.f, 0.f, 0.f};
}

// ---------------- KA: merged bitmask (blocks 0..4095) + k1 GEMM (4096..4351) --
// k1 role: H1T[c][i] bf16-hi out, plus f1/f2 epilogue (f = sum_c h[i][c]*a[c]
// over the wave's own head) -- replaces the old k0/k1c kernels.
__global__ __launch_bounds__(256)
void kA(const int* __restrict__ adj, unsigned long long* __restrict__ bm,
        const float* __restrict__ x, const float* __restrict__ w1,
        const float* __restrict__ a11, const float* __restrict__ a21,
        unsigned short* __restrict__ h1t_hi, float* __restrict__ fvals) {
    int bx = blockIdx.x;
    int tid = threadIdx.x, wave = tid >> 6, lane = tid & 63;
    if (bx < 4096) {
        int row = bx;
        #pragma unroll
        for (int it = 0; it < 16; it++) {
            int jb = it * 256 + wave * 64;
            int v = adj[row * 4096 + jb + lane];
            unsigned long long mask = __ballot(v != 0);
            if (lane == 0) bm[row * 64 + (jb >> 6)] = mask;
        }
        return;
    }
    // ---- k1 role ----
    int q = lane >> 4, m = lane & 15;
    int i0 = (bx - 4096) * 16;
    int c0 = wave * 64;                     // wave == head
    f32x4 acc[4] = {};
    #pragma unroll
    for (int k0 = 0; k0 < 256; k0 += 32) {
        bf16x8 ah, al;
        split8(x + (i0 + m) * 256 + k0 + q * 8, ah, al);
        #pragma unroll
        for (int ct = 0; ct < 4; ct++) {
            bf16x8 bh, bl;
            split8(w1 + (c0 + ct * 16 + m) * 256 + k0 + q * 8, bh, bl);
            acc[ct] = __builtin_amdgcn_mfma_f32_16x16x32_bf16(ah, bh, acc[ct], 0, 0, 0);
            acc[ct] = __builtin_amdgcn_mfma_f32_16x16x32_bf16(al, bh, acc[ct], 0, 0, 0);
            acc[ct] = __builtin_amdgcn_mfma_f32_16x16x32_bf16(ah, bl, acc[ct], 0, 0, 0);
        }
    }
    float a1v[4], a2v[4];
    #pragma unroll
    for (int ct = 0; ct < 4; ct++) {
        a1v[ct] = a11[wave * 64 + ct * 16 + m];
        a2v[ct] = a21[wave * 64 + ct * 16 + m];
    }
    #pragma unroll
    for (int r = 0; r < 4; r++) {
        int i = i0 + q * 4 + r;
        float s1 = 0.f, s2 = 0.f;
        #pragma unroll
        for (int ct = 0; ct < 4; ct++) {
            int c = c0 + ct * 16 + m;
            h1t_hi[c * 4096 + i] = f2bfh(acc[ct][r]);
            s1 += acc[ct][r] * a1v[ct];
            s2 += acc[ct][r] * a2v[ct];
        }
        #pragma unroll
        for (int off = 1; off < 16; off <<= 1) {
            s1 += __shfl_xor(s1, off);
            s2 += __shfl_xor(s2, off);
        }
        if (m == 0) {
            fvals[wave * 4096 + i] = s1;
            fvals[16384 + wave * 4096 + i] = s2;
        }
    }
}

// ---------------- attention (64-row tiles, j-split, DISJOINT partials) --------
// no-max-subtraction softmax (e bounded), P bf16-hi (A side), H bf16-hi (B).
// grid (64 i-tiles of 64 rows, heads, NJ j-chunks of JLEN); 4 waves x 16 rows.
// ATOM=false: each j-chunk writes its own partial slice (plain stores).
template<int NCT, int JLEN, bool ATOM>
__global__ __launch_bounds__(256)
void attn_kernel(const unsigned char* __restrict__ bmb,
                 const float* __restrict__ f1_all,
                 const float* __restrict__ f2_all,
                 const unsigned short* __restrict__ BTh_all,
                 float* __restrict__ pacc,
                 float* __restrict__ zacc,
                 int pstride) {
    constexpr int S   = JLEN / 32;                 // mask u32 per row
    constexpr int ST  = (S % 8 == 0) ? S + 4 : S;  // padded stride (bank-safe, 16B-aligned)
    constexpr int PR  = S / 4;                     // mask uint4 per row
    constexpr int NU4 = 64 * PR;
    int tid = threadIdx.x, wave = tid >> 6, lane = tid & 63;
    int q = lane >> 4, m = lane & 15;
    int head = blockIdx.y;
    int i0 = blockIdx.x * 64;
    int jstart = blockIdx.z * JLEN;

    if (!ATOM) {
        pacc += (size_t)blockIdx.z * (size_t)(4096 * pstride);
        zacc += (size_t)blockIdx.z * (size_t)((NCT == 4 ? 4 : 1) * 4096);
    }

    __shared__ unsigned int ldsbm[64 * ST];
    for (int c = tid; c < NU4; c += 256) {
        int row = c / PR, part = c % PR;
        uint4 v = *(const uint4*)(bmb + (size_t)(i0 + row) * 512 + (jstart >> 3) + part * 16);
        *(uint4*)&ldsbm[row * ST + part * 4] = v;
    }
    __syncthreads();

    const float* f1 = f1_all + head * 4096;
    const float* f2 = f2_all + head * 4096;
    const unsigned short* BTh = BTh_all + (size_t)head * NCT * 16 * 4096;
    int col0 = head * NCT * 16;

    int r0 = wave * 16;
    float f1s = f1[i0 + r0 + m];

    f32x4 acc[NCT] = {};
    float z = 0.f;

    #pragma unroll 2
    for (int jl = 0; jl < JLEN; jl += 32) {
        unsigned int md = ldsbm[(r0 + m) * ST + (jl >> 5)];
        const float4* f2p = (const float4*)(f2 + jstart + jl + q * 8);
        float4 fa = f2p[0], fb = f2p[1];
        float fv[8] = {fa.x, fa.y, fa.z, fa.w, fb.x, fb.y, fb.z, fb.w};
        float pv[8];
        #pragma unroll
        for (int jj = 0; jj < 8; jj++) {
            int bit = q * 8 + jj;
            float s = f1s + fv[jj];
            float e = fmaxf(s, 0.01f * s);           // leaky_relu
            bool valid = ((md >> bit) & 1u) && (s != 0.0f);
            float p = valid ? __expf(e) : 0.0f;
            z += p; pv[jj] = p;
        }
        bf16x8 ah = cvt8(pv);
        #pragma unroll
        for (int ct = 0; ct < NCT; ct++) {
            bf16x8 bh = *(const bf16x8*)(BTh + (size_t)(ct * 16 + m) * 4096 + jstart + jl + q * 8);
            acc[ct] = __builtin_amdgcn_mfma_f32_16x16x32_bf16(ah, bh, acc[ct], 0, 0, 0);
        }
    }
    z += __shfl_xor(z, 16); z += __shfl_xor(z, 32);
    if (lane < 16) {
        if (ATOM) atomicAdd(&zacc[head * 4096 + i0 + r0 + lane], z);
        else      zacc[head * 4096 + i0 + r0 + lane] = z;
    }
    #pragma unroll
    for (int ct = 0; ct < NCT; ct++)
        #pragma unroll
        for (int r = 0; r < 4; r++) {
            int col = col0 + ct * 16 + m;
            int orow = i0 + r0 + q * 4 + r;
            if (ATOM) atomicAdd(&pacc[orow * pstride + col], acc[ct][r]);
            else      pacc[orow * pstride + col] = acc[ct][r];
        }
}

// ---------------- Fin1: helu = elu(sum(p1)/sum(z1)), hi/lo bf16 ---------------
__global__ __launch_bounds__(256)
void fin1(const float* __restrict__ pp, const float* __restrict__ zp, int nj,
          unsigned short* __restrict__ hh, unsigned short* __restrict__ hl) {
    int row = blockIdx.x, col = threadIdx.x;
    float s = 0.f;
    for (int jc = 0; jc < nj; jc++) s += pp[(size_t)jc * (4096 * 256) + row * 256 + col];
    int head = col >> 6;
    float zz = 0.f;
    for (int jc = 0; jc < nj; jc++) zz += zp[jc * (4 * 4096) + head * 4096 + row];
    float v = s / zz;
    v = (v > 0.f) ? v : (__expf(v) - 1.0f);
    splitstore(&hh[row * 256 + col], &hl[row * 256 + col], v);
}

// ---------------- Fin2: out = sum(p2)/sum(z2) (f32) ---------------------------
__global__ __launch_bounds__(256)
void fin2(const float* __restrict__ pp, const float* __restrict__ zp, int nj,
          float* __restrict__ out) {
    int idx = blockIdx.x * 256 + threadIdx.x;      // 65536
    float s = 0.f;
    for (int jc = 0; jc < nj; jc++) s += pp[jc * 65536 + idx];
    float zz = 0.f;
    for (int jc = 0; jc < nj; jc++) zz += zp[jc * 4096 + (idx >> 4)];
    out[idx] = s / zz;
}

// ---------------- K3: h2 = h_elu @ W2^T (hi/lo), f1_2/f2_2, h2T hi ------------
__global__ __launch_bounds__(256)
void k3_layer2(const unsigned short* __restrict__ helu_hi,
               const unsigned short* __restrict__ helu_lo,
               const float* __restrict__ w2,
               const float* __restrict__ a12,
               const float* __restrict__ a22,
               unsigned short* __restrict__ h2t_hi,
               float* __restrict__ fq) {
    int tid = threadIdx.x, wave = tid >> 6, lane = tid & 63;
    int q = lane >> 4, m = lane & 15;
    int i0 = (blockIdx.x * 4 + wave) * 16;
    f32x4 acc = {};
    #pragma unroll
    for (int k0 = 0; k0 < 256; k0 += 32) {
        bf16x8 ah = *(const bf16x8*)(helu_hi + (i0 + m) * 256 + k0 + q * 8);
        bf16x8 al = *(const bf16x8*)(helu_lo + (i0 + m) * 256 + k0 + q * 8);
        bf16x8 bh, bl;
        split8(w2 + m * 256 + k0 + q * 8, bh, bl);
        acc = __builtin_amdgcn_mfma_f32_16x16x32_bf16(ah, bh, acc, 0, 0, 0);
        acc = __builtin_amdgcn_mfma_f32_16x16x32_bf16(al, bh, acc, 0, 0, 0);
        acc = __builtin_amdgcn_mfma_f32_16x16x32_bf16(ah, bl, acc, 0, 0, 0);
    }
    float a1v = a12[m], a2v = a22[m];
    #pragma unroll
    for (int r = 0; r < 4; r++) {
        float v = acc[r];
        int i = i0 + q * 4 + r;
        h2t_hi[m * 4096 + i] = f2bfh(v);
        float s1 = v * a1v, s2 = v * a2v;
        #pragma unroll
        for (int off = 1; off < 16; off <<= 1) {
            s1 += __shfl_xor(s1, off);
            s2 += __shfl_xor(s2, off);
        }
        if (m == 0) { fq[i] = s1; fq[4096 + i] = s2; }
    }
}

extern "C" void kernel_launch(void* const* d_in, const int* in_sizes, int n_in,
                              void* d_out, int out_size, void* d_ws, size_t ws_size,
                              hipStream_t stream) {
    const float* x   = (const float*)d_in[0];
    const int*   adj = (const int*)d_in[1];
    const float* w1  = (const float*)d_in[2];
    const float* a11 = (const float*)d_in[3];
    const float* a21 = (const float*)d_in[4];
    const float* w2  = (const float*)d_in[5];
    const float* a12 = (const float*)d_in[6];
    const float* a22 = (const float*)d_in[7];
    float* out = (float*)d_out;

    uint8_t* w = (uint8_t*)d_ws;
    unsigned long long* bm  = (unsigned long long*)(w);                       // 2 MB
    unsigned short* h1t_hi  = (unsigned short*)(w + (2u << 20));              // 2 MB
    unsigned short* helu_hi = (unsigned short*)(w + (4u << 20));              // 2 MB
    unsigned short* helu_lo = (unsigned short*)(w + (6u << 20));              // 2 MB
    unsigned short* h2t_hi  = (unsigned short*)(w + (8u << 20));              // 128 KB
    float*          fvals   = (float*)(w + (8u << 20) + (128u << 10));        // 128 KB
    float*          fq      = (float*)(w + (8u << 20) + (256u << 10));        // 32 KB

    bool big = ws_size >= ((size_t)46 << 20);
    float* p1 = (float*)(w + (8u << 20) + (320u << 10));
    float *z1, *p2, *z2;
    if (big) {
        z1 = p1 + (size_t)8 * 4096 * 256;       // p1: 8 x 4 MB = 32 MB
        p2 = z1 + 8 * 4 * 4096;                 // z1: 8 x 64 KB
        z2 = p2 + (size_t)16 * 4096 * 16;       // p2: 16 x 256 KB = 4 MB
    } else {
        z1 = p1 + 4096 * 256;                   // p1: 4 MB
        p2 = z1 + 4 * 4096;                     // z1: 64 KB
        z2 = p2 + 4096 * 16;                    // p2: 256 KB, z2: 16 KB
    }

    if (!big) kzero<<<1108, 256, 0, stream>>>((float4*)p1);
    kA<<<4352, 256, 0, stream>>>(adj, bm, x, w1, a11, a21, h1t_hi, fvals);
    if (big)
        attn_kernel<4, 512, false><<<dim3(64, 4, 8), 256, 0, stream>>>(
            (const unsigned char*)bm, fvals, fvals + 4 * 4096, h1t_hi, p1, z1, 256);
    else
        attn_kernel<4, 512, true><<<dim3(64, 4, 8), 256, 0, stream>>>(
            (const unsigned char*)bm, fvals, fvals + 4 * 4096, h1t_hi, p1, z1, 256);
    fin1<<<4096, 256, 0, stream>>>(p1, z1, big ? 8 : 1, helu_hi, helu_lo);
    k3_layer2<<<64, 256, 0, stream>>>(helu_hi, helu_lo, w2, a12, a22,
                                      h2t_hi, fq);
    if (big)
        attn_kernel<1, 256, false><<<dim3(64, 1, 16), 256, 0, stream>>>(
            (const unsigned char*)bm, fq, fq + 4096, h2t_hi, p2, z2, 16);
    else
        attn_kernel<1, 256, true><<<dim3(64, 1, 16), 256, 0, stream>>>(
            (const unsigned char*)bm, fq, fq + 4096, h2t_hi, p2, z2, 16);
    fin2<<<256, 256, 0, stream>>>(p2, z2, big ? 16 : 1, out);
}

// Round 8
// 220.538 us; speedup vs baseline: 1.1701x; 1.1701x over previous
//
#include <hip/hip_runtime.h>
#include <cstdint>

typedef __bf16 bf16x8 __attribute__((ext_vector_type(8)));
typedef float  f32x4  __attribute__((ext_vector_type(4)));

// split 8 f32 into hi/lo bf16 fragments (hi+lo ~ 16-bit mantissa)
__device__ __forceinline__ void split8(const float* v, bf16x8& hi, bf16x8& lo) {
    union { bf16x8 v; __bf16 e[8]; } h, l;
    #pragma unroll
    for (int j = 0; j < 8; j++) {
        __bf16 hb = (__bf16)v[j];
        float  r  = v[j] - (float)hb;
        h.e[j] = hb; l.e[j] = (__bf16)r;
    }
    hi = h.v; lo = l.v;
}
__device__ __forceinline__ bf16x8 cvt8(const float* v) {
    union { bf16x8 v; __bf16 e[8]; } u;
    #pragma unroll
    for (int j = 0; j < 8; j++) u.e[j] = (__bf16)v[j];
    return u.v;
}
__device__ __forceinline__ void splitstore(unsigned short* ph, unsigned short* pl, float v) {
    __bf16 hb = (__bf16)v;
    float  r  = v - (float)hb;
    __bf16 lb = (__bf16)r;
    unsigned short hu, lu;
    __builtin_memcpy(&hu, &hb, 2); __builtin_memcpy(&lu, &lb, 2);
    *ph = hu; *pl = lu;
}
__device__ __forceinline__ unsigned short f2bfh(float v) {
    __bf16 hb = (__bf16)v; unsigned short hu;
    __builtin_memcpy(&hu, &hb, 2); return hu;
}

// ---------------- Kzero: zero the atomic-accumulation region (fallback) -------
__global__ __launch_bounds__(256)
void kzero(float4* __restrict__ p) {
    p[blockIdx.x * 256 + threadIdx.x] = float4{0.f, 0.f, 0.f, 0.f};
}

// ---------------- Kpre: bitmask bitpack (blocks 0..2047) + weight split -------
// One thread per u32 mask word (32 consecutive j via 8 int4 loads, no ballot).
__global__ __launch_bounds__(256)
void kpre(const int* __restrict__ adj, unsigned int* __restrict__ bm32,
          const float* __restrict__ w1, const float* __restrict__ w2,
          unsigned short* __restrict__ w1h, unsigned short* __restrict__ w1l,
          unsigned short* __restrict__ w2h, unsigned short* __restrict__ w2l) {
    int bx = blockIdx.x, tid = threadIdx.x;
    if (bx < 2048) {
        int word = bx * 256 + tid;                  // 524288 words
        int row = word >> 7, wj = (word & 127) * 32;
        const int* base = adj + (size_t)row * 4096 + wj;
        unsigned int acc = 0;
        #pragma unroll
        for (int it = 0; it < 8; it++) {
            int4 v = *(const int4*)(base + it * 4);
            acc |= (unsigned int)(v.x != 0) << (it * 4 + 0);
            acc |= (unsigned int)(v.y != 0) << (it * 4 + 1);
            acc |= (unsigned int)(v.z != 0) << (it * 4 + 2);
            acc |= (unsigned int)(v.w != 0) << (it * 4 + 3);
        }
        bm32[word] = acc;
        return;
    }
    // weight split role: 68 blocks x 256 thr x 4 elems = 69632 (w1 65536 + w2 4096)
    int e = ((bx - 2048) * 256 + tid) * 4;
    const float* src; unsigned short *dh, *dl;
    if (e < 65536) { src = w1 + e; dh = w1h + e; dl = w1l + e; }
    else { int e2 = e - 65536; src = w2 + e2; dh = w2h + e2; dl = w2l + e2; }
    #pragma unroll
    for (int j = 0; j < 4; j++) splitstore(dh + j, dl + j, src[j]);
}

// ---------------- K1: H1T[c][i] = (x @ W1^T)[i][c] bf16-hi, + f1/f2 epilogue --
__global__ __launch_bounds__(256)
void k1_gemm(const float* __restrict__ x,
             const unsigned short* __restrict__ w1h,
             const unsigned short* __restrict__ w1l,
             const float* __restrict__ a11, const float* __restrict__ a21,
             unsigned short* __restrict__ h1t_hi, float* __restrict__ fvals) {
    int tid = threadIdx.x, wave = tid >> 6, lane = tid & 63;
    int q = lane >> 4, m = lane & 15;
    int i0 = blockIdx.x * 16;
    int c0 = wave * 64;                     // wave == head
    f32x4 acc[4] = {};
    #pragma unroll
    for (int k0 = 0; k0 < 256; k0 += 32) {
        bf16x8 ah, al;
        split8(x + (i0 + m) * 256 + k0 + q * 8, ah, al);
        #pragma unroll
        for (int ct = 0; ct < 4; ct++) {
            bf16x8 bh = *(const bf16x8*)(w1h + (c0 + ct * 16 + m) * 256 + k0 + q * 8);
            bf16x8 bl = *(const bf16x8*)(w1l + (c0 + ct * 16 + m) * 256 + k0 + q * 8);
            acc[ct] = __builtin_amdgcn_mfma_f32_16x16x32_bf16(ah, bh, acc[ct], 0, 0, 0);
            acc[ct] = __builtin_amdgcn_mfma_f32_16x16x32_bf16(al, bh, acc[ct], 0, 0, 0);
            acc[ct] = __builtin_amdgcn_mfma_f32_16x16x32_bf16(ah, bl, acc[ct], 0, 0, 0);
        }
    }
    float a1v[4], a2v[4];
    #pragma unroll
    for (int ct = 0; ct < 4; ct++) {
        a1v[ct] = a11[wave * 64 + ct * 16 + m];
        a2v[ct] = a21[wave * 64 + ct * 16 + m];
    }
    #pragma unroll
    for (int r = 0; r < 4; r++) {
        int i = i0 + q * 4 + r;
        float s1 = 0.f, s2 = 0.f;
        #pragma unroll
        for (int ct = 0; ct < 4; ct++) {
            int c = c0 + ct * 16 + m;
            h1t_hi[c * 4096 + i] = f2bfh(acc[ct][r]);
            s1 += acc[ct][r] * a1v[ct];
            s2 += acc[ct][r] * a2v[ct];
        }
        #pragma unroll
        for (int off = 1; off < 16; off <<= 1) {
            s1 += __shfl_xor(s1, off);
            s2 += __shfl_xor(s2, off);
        }
        if (m == 0) {
            fvals[wave * 4096 + i] = s1;
            fvals[16384 + wave * 4096 + i] = s2;
        }
    }
}

// ---------------- attention (128-row tiles, j-split, DISJOINT partials) -------
// no-max-subtraction softmax (e bounded), P bf16-hi (A side), H bf16-hi (B).
// grid (32 i-tiles of 128 rows, heads, 4096/JLEN chunks); 4 waves x 2 row-frags.
template<int NCT, int JLEN, bool ATOM>
__global__ __launch_bounds__(256)
void attn_kernel(const unsigned char* __restrict__ bmb,
                 const float* __restrict__ f1_all,
                 const float* __restrict__ f2_all,
                 const unsigned short* __restrict__ BTh_all,
                 float* __restrict__ pacc,
                 float* __restrict__ zacc,
                 int pstride) {
    constexpr int S   = JLEN / 32;                 // mask u32 per row
    constexpr int ST  = (S % 8 == 0) ? S + 4 : S;  // bank-safe padded stride
    constexpr int PR  = S / 4;                     // mask uint4 per row
    constexpr int NU4 = 128 * PR;
    int tid = threadIdx.x, wave = tid >> 6, lane = tid & 63;
    int q = lane >> 4, m = lane & 15;
    int head = blockIdx.y;
    int i0 = blockIdx.x * 128;
    int jstart = blockIdx.z * JLEN;

    if (!ATOM) {
        pacc += (size_t)blockIdx.z * (size_t)(4096 * pstride);
        zacc += (size_t)blockIdx.z * (size_t)((NCT == 4 ? 4 : 1) * 4096);
    }

    __shared__ unsigned int ldsbm[128 * ST];
    for (int c = tid; c < NU4; c += 256) {
        int row = c / PR, part = c % PR;
        uint4 v = *(const uint4*)(bmb + (size_t)(i0 + row) * 512 + (jstart >> 3) + part * 16);
        *(uint4*)&ldsbm[row * ST + part * 4] = v;
    }
    __syncthreads();

    const float* f1 = f1_all + head * 4096;
    const float* f2 = f2_all + head * 4096;
    const unsigned short* BTh = BTh_all + (size_t)head * NCT * 16 * 4096;
    int col0 = head * NCT * 16;

    int r0 = wave * 32;
    float f1s0 = f1[i0 + r0 + m];
    float f1s1 = f1[i0 + r0 + 16 + m];

    f32x4 acc0[NCT] = {}, acc1[NCT] = {};
    float z0 = 0.f, z1 = 0.f;

    #pragma unroll 2
    for (int jl = 0; jl < JLEN; jl += 32) {
        unsigned int md0 = ldsbm[(r0 + m) * ST + (jl >> 5)];
        unsigned int md1 = ldsbm[(r0 + 16 + m) * ST + (jl >> 5)];
        const float4* f2p = (const float4*)(f2 + jstart + jl + q * 8);
        float4 fa = f2p[0], fb = f2p[1];
        float fv[8] = {fa.x, fa.y, fa.z, fa.w, fb.x, fb.y, fb.z, fb.w};
        float pv0[8], pv1[8];
        #pragma unroll
        for (int jj = 0; jj < 8; jj++) {
            int bit = q * 8 + jj;
            float s0 = f1s0 + fv[jj];
            float e0 = fmaxf(s0, 0.01f * s0);            // leaky_relu
            bool v0 = ((md0 >> bit) & 1u) && (s0 != 0.0f);
            float p0 = v0 ? __expf(e0) : 0.0f;
            z0 += p0; pv0[jj] = p0;
            float s1 = f1s1 + fv[jj];
            float e1 = fmaxf(s1, 0.01f * s1);
            bool v1 = ((md1 >> bit) & 1u) && (s1 != 0.0f);
            float p1 = v1 ? __expf(e1) : 0.0f;
            z1 += p1; pv1[jj] = p1;
        }
        bf16x8 ah0 = cvt8(pv0), ah1 = cvt8(pv1);
        #pragma unroll
        for (int ct = 0; ct < NCT; ct++) {
            bf16x8 bh = *(const bf16x8*)(BTh + (size_t)(ct * 16 + m) * 4096 + jstart + jl + q * 8);
            acc0[ct] = __builtin_amdgcn_mfma_f32_16x16x32_bf16(ah0, bh, acc0[ct], 0, 0, 0);
            acc1[ct] = __builtin_amdgcn_mfma_f32_16x16x32_bf16(ah1, bh, acc1[ct], 0, 0, 0);
        }
    }
    z0 += __shfl_xor(z0, 16); z0 += __shfl_xor(z0, 32);
    z1 += __shfl_xor(z1, 16); z1 += __shfl_xor(z1, 32);
    if (lane < 16) {
        if (ATOM) {
            atomicAdd(&zacc[head * 4096 + i0 + r0 + lane], z0);
            atomicAdd(&zacc[head * 4096 + i0 + r0 + 16 + lane], z1);
        } else {
            zacc[head * 4096 + i0 + r0 + lane] = z0;
            zacc[head * 4096 + i0 + r0 + 16 + lane] = z1;
        }
    }
    #pragma unroll
    for (int ct = 0; ct < NCT; ct++)
        #pragma unroll
        for (int r = 0; r < 4; r++) {
            int col = col0 + ct * 16 + m;
            int rowA = i0 + r0 + q * 4 + r;
            if (ATOM) {
                atomicAdd(&pacc[rowA * pstride + col], acc0[ct][r]);
                atomicAdd(&pacc[(rowA + 16) * pstride + col], acc1[ct][r]);
            } else {
                pacc[rowA * pstride + col] = acc0[ct][r];
                pacc[(rowA + 16) * pstride + col] = acc1[ct][r];
            }
        }
}

// ---------------- K3 (fused fin1): helu = elu(sum p1 / sum z1) in-register, ---
// h2 = helu @ W2^T (hi/lo x hi/lo, 3 MFMA), f1_2/f2_2 epilogue, h2T bf16-hi.
__global__ __launch_bounds__(256)
void k3_fused(const float* __restrict__ pp, const float* __restrict__ zp, int nj,
              const unsigned short* __restrict__ w2h,
              const unsigned short* __restrict__ w2l,
              const float* __restrict__ a12, const float* __restrict__ a22,
              unsigned short* __restrict__ h2t_hi, float* __restrict__ fq) {
    int tid = threadIdx.x, wave = tid >> 6, lane = tid & 63;
    int q = lane >> 4, m = lane & 15;
    int i0 = (blockIdx.x * 4 + wave) * 16;
    int row = i0 + m;
    float rz[4];
    #pragma unroll
    for (int h = 0; h < 4; h++) {
        float zz = 0.f;
        for (int s = 0; s < nj; s++) zz += zp[s * 16384 + h * 4096 + row];
        rz[h] = 1.0f / zz;
    }
    f32x4 acc = {};
    #pragma unroll
    for (int k0 = 0; k0 < 256; k0 += 32) {
        int cb = k0 + q * 8;
        float4 sa = {0.f, 0.f, 0.f, 0.f}, sb = {0.f, 0.f, 0.f, 0.f};
        for (int s = 0; s < nj; s++) {
            const float4* p = (const float4*)(pp + (size_t)s * (4096 * 256) + row * 256 + cb);
            float4 va = p[0], vb = p[1];
            sa.x += va.x; sa.y += va.y; sa.z += va.z; sa.w += va.w;
            sb.x += vb.x; sb.y += vb.y; sb.z += vb.z; sb.w += vb.w;
        }
        float r = rz[cb >> 6];
        float hv[8] = {sa.x * r, sa.y * r, sa.z * r, sa.w * r,
                       sb.x * r, sb.y * r, sb.z * r, sb.w * r};
        #pragma unroll
        for (int jj = 0; jj < 8; jj++)
            hv[jj] = (hv[jj] > 0.f) ? hv[jj] : (__expf(hv[jj]) - 1.0f);   // elu
        bf16x8 ah, al;
        split8(hv, ah, al);
        bf16x8 bh = *(const bf16x8*)(w2h + m * 256 + cb);
        bf16x8 bl = *(const bf16x8*)(w2l + m * 256 + cb);
        acc = __builtin_amdgcn_mfma_f32_16x16x32_bf16(ah, bh, acc, 0, 0, 0);
        acc = __builtin_amdgcn_mfma_f32_16x16x32_bf16(al, bh, acc, 0, 0, 0);
        acc = __builtin_amdgcn_mfma_f32_16x16x32_bf16(ah, bl, acc, 0, 0, 0);
    }
    float a1v = a12[m], a2v = a22[m];
    #pragma unroll
    for (int r = 0; r < 4; r++) {
        float v = acc[r];
        int i = i0 + q * 4 + r;
        h2t_hi[m * 4096 + i] = f2bfh(v);
        float s1 = v * a1v, s2 = v * a2v;
        #pragma unroll
        for (int off = 1; off < 16; off <<= 1) {
            s1 += __shfl_xor(s1, off);
            s2 += __shfl_xor(s2, off);
        }
        if (m == 0) { fq[i] = s1; fq[4096 + i] = s2; }
    }
}

// ---------------- Fin2: out = sum(p2)/sum(z2) (f32) ---------------------------
__global__ __launch_bounds__(256)
void fin2(const float* __restrict__ pp, const float* __restrict__ zp, int nj,
          float* __restrict__ out) {
    int idx = blockIdx.x * 256 + threadIdx.x;      // 65536
    float s = 0.f;
    for (int jc = 0; jc < nj; jc++) s += pp[jc * 65536 + idx];
    float zz = 0.f;
    for (int jc = 0; jc < nj; jc++) zz += zp[jc * 4096 + (idx >> 4)];
    out[idx] = s / zz;
}

extern "C" void kernel_launch(void* const* d_in, const int* in_sizes, int n_in,
                              void* d_out, int out_size, void* d_ws, size_t ws_size,
                              hipStream_t stream) {
    const float* x   = (const float*)d_in[0];
    const int*   adj = (const int*)d_in[1];
    const float* w1  = (const float*)d_in[2];
    const float* a11 = (const float*)d_in[3];
    const float* a21 = (const float*)d_in[4];
    const float* w2  = (const float*)d_in[5];
    const float* a12 = (const float*)d_in[6];
    const float* a22 = (const float*)d_in[7];
    float* out = (float*)d_out;

    uint8_t* w = (uint8_t*)d_ws;
    unsigned int*   bm32    = (unsigned int*)(w);                             // 2 MB
    unsigned short* h1t_hi  = (unsigned short*)(w + (2u << 20));              // 2 MB
    unsigned short* h2t_hi  = (unsigned short*)(w + (4u << 20));              // 128 KB
    float*          fvals   = (float*)(w + (4u << 20) + (128u << 10));        // 128 KB
    float*          fq      = (float*)(w + (4u << 20) + (256u << 10));        // 32 KB
    unsigned short* w1h     = (unsigned short*)(w + (4u << 20) + (288u << 10)); // 128 KB
    unsigned short* w1l     = (unsigned short*)(w + (4u << 20) + (416u << 10)); // 128 KB
    unsigned short* w2h     = (unsigned short*)(w + (4u << 20) + (544u << 10)); // 8 KB
    unsigned short* w2l     = (unsigned short*)(w + (4u << 20) + (552u << 10)); // 8 KB

    bool big = ws_size >= ((size_t)46 << 20);
    float* p1 = (float*)(w + (5u << 20));
    float *z1, *p2, *z2;
    if (big) {
        z1 = p1 + (size_t)8 * 4096 * 256;       // p1: 8 x 4 MB = 32 MB
        p2 = z1 + 8 * 4 * 4096;                 // z1: 8 x 64 KB
        z2 = p2 + (size_t)16 * 4096 * 16;       // p2: 16 x 256 KB = 4 MB
    } else {
        z1 = p1 + 4096 * 256;                   // p1: 4 MB
        p2 = z1 + 4 * 4096;                     // z1: 64 KB
        z2 = p2 + 4096 * 16;                    // p2: 256 KB, z2: 16 KB
    }

    if (!big) kzero<<<1108, 256, 0, stream>>>((float4*)p1);
    kpre<<<2116, 256, 0, stream>>>(adj, bm32, w1, w2, w1h, w1l, w2h, w2l);
    k1_gemm<<<256, 256, 0, stream>>>(x, w1h, w1l, a11, a21, h1t_hi, fvals);
    if (big)
        attn_kernel<4, 512, false><<<dim3(32, 4, 8), 256, 0, stream>>>(
            (const unsigned char*)bm32, fvals, fvals + 16384, h1t_hi, p1, z1, 256);
    else
        attn_kernel<4, 512, true><<<dim3(32, 4, 8), 256, 0, stream>>>(
            (const unsigned char*)bm32, fvals, fvals + 16384, h1t_hi, p1, z1, 256);
    k3_fused<<<64, 256, 0, stream>>>(p1, z1, big ? 8 : 1, w2h, w2l, a12, a22,
                                     h2t_hi, fq);
    if (big)
        attn_kernel<1, 256, false><<<dim3(32, 1, 16), 256, 0, stream>>>(
            (const unsigned char*)bm32, fq, fq + 4096, h2t_hi, p2, z2, 16);
    else
        attn_kernel<1, 256, true><<<dim3(32, 1, 16), 256, 0, stream>>>(
            (const unsigned char*)bm32, fq, fq + 4096, h2t_hi, p2, z2, 16);
    fin2<<<256, 256, 0, stream>>>(p2, z2, big ? 16 : 1, out);
}

// Round 9
// 200.956 us; speedup vs baseline: 1.2841x; 1.0974x over previous
//
#include <hip/hip_runtime.h>
#include <cstdint>

typedef __bf16 bf16x8 __attribute__((ext_vector_type(8)));
typedef float  f32x4  __attribute__((ext_vector_type(4)));

// split 8 f32 into hi/lo bf16 fragments (hi+lo ~ 16-bit mantissa)
__device__ __forceinline__ void split8(const float* v, bf16x8& hi, bf16x8& lo) {
    union { bf16x8 v; __bf16 e[8]; } h, l;
    #pragma unroll
    for (int j = 0; j < 8; j++) {
        __bf16 hb = (__bf16)v[j];
        float  r  = v[j] - (float)hb;
        h.e[j] = hb; l.e[j] = (__bf16)r;
    }
    hi = h.v; lo = l.v;
}
__device__ __forceinline__ bf16x8 cvt8(const float* v) {
    union { bf16x8 v; __bf16 e[8]; } u;
    #pragma unroll
    for (int j = 0; j < 8; j++) u.e[j] = (__bf16)v[j];
    return u.v;
}
__device__ __forceinline__ void splitstore(unsigned short* ph, unsigned short* pl, float v) {
    __bf16 hb = (__bf16)v;
    float  r  = v - (float)hb;
    __bf16 lb = (__bf16)r;
    unsigned short hu, lu;
    __builtin_memcpy(&hu, &hb, 2); __builtin_memcpy(&lu, &lb, 2);
    *ph = hu; *pl = lu;
}
__device__ __forceinline__ unsigned short f2bfh(float v) {
    __bf16 hb = (__bf16)v; unsigned short hu;
    __builtin_memcpy(&hu, &hb, 2); return hu;
}

// ---------------- Kzero: zero the atomic-accumulation region (fallback) -------
__global__ __launch_bounds__(256)
void kzero(float4* __restrict__ p) {
    p[blockIdx.x * 256 + threadIdx.x] = float4{0.f, 0.f, 0.f, 0.f};
}

// ---------------- Kpre: ballot bitpack (blocks 0..8191) + weight split --------
// Wave reads 64 consecutive ints (coalesced, fully-used lines); __ballot packs.
__global__ __launch_bounds__(256)
void kpre(const int* __restrict__ adj, unsigned long long* __restrict__ bm64,
          const float* __restrict__ w1, const float* __restrict__ w2,
          unsigned short* __restrict__ w1h, unsigned short* __restrict__ w1l,
          unsigned short* __restrict__ w2h, unsigned short* __restrict__ w2l) {
    int bx = blockIdx.x, tid = threadIdx.x;
    if (bx < 8192) {
        int row = bx >> 1, jbase = (bx & 1) * 2048;
        int wave = tid >> 6, lane = tid & 63;
        const int* base = adj + (size_t)row * 4096 + jbase + wave * 512;
        unsigned long long* bmw = bm64 + row * 64 + (jbase >> 6) + wave * 8;
        #pragma unroll
        for (int it = 0; it < 8; it++) {
            int v = base[it * 64 + lane];
            unsigned long long mask = __ballot(v != 0);
            if (lane == 0) bmw[it] = mask;
        }
        return;
    }
    // weight split role: 68 blocks x 256 thr x 4 = 69632 (w1 65536 + w2 4096)
    int e = ((bx - 8192) * 256 + tid) * 4;
    const float* src; unsigned short *dh, *dl;
    if (e < 65536) { src = w1 + e; dh = w1h + e; dl = w1l + e; }
    else { int e2 = e - 65536; src = w2 + e2; dh = w2h + e2; dl = w2l + e2; }
    #pragma unroll
    for (int j = 0; j < 4; j++) splitstore(dh + j, dl + j, src[j]);
}

// ---------------- K1: H1T[c][i] = (x @ W1^T)[i][c] bf16-hi, + f1/f2 epilogue --
__global__ __launch_bounds__(256)
void k1_gemm(const float* __restrict__ x,
             const unsigned short* __restrict__ w1h,
             const unsigned short* __restrict__ w1l,
             const float* __restrict__ a11, const float* __restrict__ a21,
             unsigned short* __restrict__ h1t_hi, float* __restrict__ fvals) {
    int tid = threadIdx.x, wave = tid >> 6, lane = tid & 63;
    int q = lane >> 4, m = lane & 15;
    int i0 = blockIdx.x * 16;
    int c0 = wave * 64;                     // wave == head
    f32x4 acc[4] = {};
    #pragma unroll
    for (int k0 = 0; k0 < 256; k0 += 32) {
        bf16x8 ah, al;
        split8(x + (i0 + m) * 256 + k0 + q * 8, ah, al);
        #pragma unroll
        for (int ct = 0; ct < 4; ct++) {
            bf16x8 bh = *(const bf16x8*)(w1h + (c0 + ct * 16 + m) * 256 + k0 + q * 8);
            bf16x8 bl = *(const bf16x8*)(w1l + (c0 + ct * 16 + m) * 256 + k0 + q * 8);
            acc[ct] = __builtin_amdgcn_mfma_f32_16x16x32_bf16(ah, bh, acc[ct], 0, 0, 0);
            acc[ct] = __builtin_amdgcn_mfma_f32_16x16x32_bf16(al, bh, acc[ct], 0, 0, 0);
            acc[ct] = __builtin_amdgcn_mfma_f32_16x16x32_bf16(ah, bl, acc[ct], 0, 0, 0);
        }
    }
    float a1v[4], a2v[4];
    #pragma unroll
    for (int ct = 0; ct < 4; ct++) {
        a1v[ct] = a11[wave * 64 + ct * 16 + m];
        a2v[ct] = a21[wave * 64 + ct * 16 + m];
    }
    #pragma unroll
    for (int r = 0; r < 4; r++) {
        int i = i0 + q * 4 + r;
        float s1 = 0.f, s2 = 0.f;
        #pragma unroll
        for (int ct = 0; ct < 4; ct++) {
            int c = c0 + ct * 16 + m;
            h1t_hi[c * 4096 + i] = f2bfh(acc[ct][r]);
            s1 += acc[ct][r] * a1v[ct];
            s2 += acc[ct][r] * a2v[ct];
        }
        #pragma unroll
        for (int off = 1; off < 16; off <<= 1) {
            s1 += __shfl_xor(s1, off);
            s2 += __shfl_xor(s2, off);
        }
        if (m == 0) {
            fvals[wave * 4096 + i] = s1;
            fvals[16384 + wave * 4096 + i] = s2;
        }
    }
}

// ---------------- attention (128-row tiles, j-split, LDS-staged BT) -----------
// no-max-subtraction softmax (e bounded), P bf16-hi (A side), H bf16-hi (B).
// BT tiles (CR x 32 j) double-buffered in LDS: coalesced loads, no 4-wave
// redundancy, no 16-line gathers. grid (32 i-tiles, heads, 4096/JLEN chunks).
template<int NCT, int JLEN, bool ATOM>
__global__ __launch_bounds__(256)
void attn_kernel(const unsigned char* __restrict__ bmb,
                 const float* __restrict__ f1_all,
                 const float* __restrict__ f2_all,
                 const unsigned short* __restrict__ BTh_all,
                 float* __restrict__ pacc,
                 float* __restrict__ zacc,
                 int pstride) {
    constexpr int S    = JLEN / 32;                 // mask u32 per row
    constexpr int ST   = (S % 8 == 0) ? S + 4 : S;  // bank-safe padded stride
    constexpr int PR   = S / 4;                     // mask uint4 per row
    constexpr int NU4  = 128 * PR;
    constexpr int CR   = NCT * 16;                  // BT tile rows
    constexpr int TSTR = 40;                        // tile row stride (halfwords, 80 B)
    int tid = threadIdx.x, wave = tid >> 6, lane = tid & 63;
    int q = lane >> 4, m = lane & 15;
    int head = blockIdx.y;
    int i0 = blockIdx.x * 128;
    int jstart = blockIdx.z * JLEN;

    if (!ATOM) {
        pacc += (size_t)blockIdx.z * (size_t)(4096 * pstride);
        zacc += (size_t)blockIdx.z * (size_t)((NCT == 4 ? 4 : 1) * 4096);
    }

    __shared__ unsigned int ldsbm[128 * ST];
    __shared__ unsigned short ldsbt[2][CR * TSTR];

    const unsigned short* BTh = BTh_all + (size_t)head * CR * 4096;

    // stage bitmask slice
    for (int c = tid; c < NU4; c += 256) {
        int row = c / PR, part = c % PR;
        uint4 v = *(const uint4*)(bmb + (size_t)(i0 + row) * 512 + (jstart >> 3) + part * 16);
        *(uint4*)&ldsbm[row * ST + part * 4] = v;
    }
    // stage BT tile 0
    uint4 vstage;
    int sc = tid >> 2, sp = tid & 3;
    if (tid < CR * 4) {
        vstage = *(const uint4*)(BTh + (size_t)sc * 4096 + jstart + sp * 8);
        *(uint4*)&ldsbt[0][sc * TSTR + sp * 8] = vstage;
    }

    const float* f1 = f1_all + head * 4096;
    const float* f2 = f2_all + head * 4096;
    int col0 = head * CR;

    int r0 = wave * 32;
    float f1s0 = f1[i0 + r0 + m];
    float f1s1 = f1[i0 + r0 + 16 + m];

    f32x4 acc0[NCT] = {}, acc1[NCT] = {};
    float z0 = 0.f, z1 = 0.f;

    constexpr int NIT = JLEN / 32;
    for (int it = 0; it < NIT; it++) {
        __syncthreads();
        int jl = it * 32;
        // issue next tile's global loads early (latency hidden under compute)
        if (it + 1 < NIT && tid < CR * 4)
            vstage = *(const uint4*)(BTh + (size_t)sc * 4096 + jstart + jl + 32 + sp * 8);

        unsigned int md0 = ldsbm[(r0 + m) * ST + (jl >> 5)];
        unsigned int md1 = ldsbm[(r0 + 16 + m) * ST + (jl >> 5)];
        const float4* f2p = (const float4*)(f2 + jstart + jl + q * 8);
        float4 fa = f2p[0], fb = f2p[1];
        float fv[8] = {fa.x, fa.y, fa.z, fa.w, fb.x, fb.y, fb.z, fb.w};
        float pv0[8], pv1[8];
        #pragma unroll
        for (int jj = 0; jj < 8; jj++) {
            int bit = q * 8 + jj;
            float s0 = f1s0 + fv[jj];
            float e0 = fmaxf(s0, 0.01f * s0);            // leaky_relu
            bool v0 = ((md0 >> bit) & 1u) && (s0 != 0.0f);
            float p0 = v0 ? __expf(e0) : 0.0f;
            z0 += p0; pv0[jj] = p0;
            float s1 = f1s1 + fv[jj];
            float e1 = fmaxf(s1, 0.01f * s1);
            bool v1 = ((md1 >> bit) & 1u) && (s1 != 0.0f);
            float p1 = v1 ? __expf(e1) : 0.0f;
            z1 += p1; pv1[jj] = p1;
        }
        bf16x8 ah0 = cvt8(pv0), ah1 = cvt8(pv1);
        int cur = it & 1;
        #pragma unroll
        for (int ct = 0; ct < NCT; ct++) {
            bf16x8 bh = *(const bf16x8*)&ldsbt[cur][(ct * 16 + m) * TSTR + q * 8];
            acc0[ct] = __builtin_amdgcn_mfma_f32_16x16x32_bf16(ah0, bh, acc0[ct], 0, 0, 0);
            acc1[ct] = __builtin_amdgcn_mfma_f32_16x16x32_bf16(ah1, bh, acc1[ct], 0, 0, 0);
        }
        if (it + 1 < NIT && tid < CR * 4)
            *(uint4*)&ldsbt[1 - cur][sc * TSTR + sp * 8] = vstage;
    }
    z0 += __shfl_xor(z0, 16); z0 += __shfl_xor(z0, 32);
    z1 += __shfl_xor(z1, 16); z1 += __shfl_xor(z1, 32);
    if (lane < 16) {
        if (ATOM) {
            atomicAdd(&zacc[head * 4096 + i0 + r0 + lane], z0);
            atomicAdd(&zacc[head * 4096 + i0 + r0 + 16 + lane], z1);
        } else {
            zacc[head * 4096 + i0 + r0 + lane] = z0;
            zacc[head * 4096 + i0 + r0 + 16 + lane] = z1;
        }
    }
    #pragma unroll
    for (int ct = 0; ct < NCT; ct++)
        #pragma unroll
        for (int r = 0; r < 4; r++) {
            int col = col0 + ct * 16 + m;
            int rowA = i0 + r0 + q * 4 + r;
            if (ATOM) {
                atomicAdd(&pacc[rowA * pstride + col], acc0[ct][r]);
                atomicAdd(&pacc[(rowA + 16) * pstride + col], acc1[ct][r]);
            } else {
                pacc[rowA * pstride + col] = acc0[ct][r];
                pacc[(rowA + 16) * pstride + col] = acc1[ct][r];
            }
        }
}

// ---------------- Fin1c: helu = elu(sum p1 / sum z1), coalesced, hi/lo bf16 ---
__global__ __launch_bounds__(256)
void fin1c(const float* __restrict__ pp, const float* __restrict__ zp, int nj,
           unsigned short* __restrict__ hh, unsigned short* __restrict__ hl) {
    int row = blockIdx.x, col = threadIdx.x;
    float s = 0.f;
    for (int jc = 0; jc < nj; jc++) s += pp[(size_t)jc * (4096 * 256) + row * 256 + col];
    int head = col >> 6;
    float zz = 0.f;
    for (int jc = 0; jc < nj; jc++) zz += zp[jc * (4 * 4096) + head * 4096 + row];
    float v = s / zz;
    v = (v > 0.f) ? v : (__expf(v) - 1.0f);
    splitstore(&hh[row * 256 + col], &hl[row * 256 + col], v);
}

// ---------------- K3: h2 = h_elu @ W2^T (hi/lo), f1_2/f2_2, h2T bf16-hi -------
__global__ __launch_bounds__(256)
void k3_layer2(const unsigned short* __restrict__ helu_hi,
               const unsigned short* __restrict__ helu_lo,
               const unsigned short* __restrict__ w2h,
               const unsigned short* __restrict__ w2l,
               const float* __restrict__ a12,
               const float* __restrict__ a22,
               unsigned short* __restrict__ h2t_hi,
               float* __restrict__ fq) {
    int tid = threadIdx.x, wave = tid >> 6, lane = tid & 63;
    int q = lane >> 4, m = lane & 15;
    int i0 = (blockIdx.x * 4 + wave) * 16;
    f32x4 acc = {};
    #pragma unroll
    for (int k0 = 0; k0 < 256; k0 += 32) {
        bf16x8 ah = *(const bf16x8*)(helu_hi + (i0 + m) * 256 + k0 + q * 8);
        bf16x8 al = *(const bf16x8*)(helu_lo + (i0 + m) * 256 + k0 + q * 8);
        bf16x8 bh = *(const bf16x8*)(w2h + m * 256 + k0 + q * 8);
        bf16x8 bl = *(const bf16x8*)(w2l + m * 256 + k0 + q * 8);
        acc = __builtin_amdgcn_mfma_f32_16x16x32_bf16(ah, bh, acc, 0, 0, 0);
        acc = __builtin_amdgcn_mfma_f32_16x16x32_bf16(al, bh, acc, 0, 0, 0);
        acc = __builtin_amdgcn_mfma_f32_16x16x32_bf16(ah, bl, acc, 0, 0, 0);
    }
    float a1v = a12[m], a2v = a22[m];
    #pragma unroll
    for (int r = 0; r < 4; r++) {
        float v = acc[r];
        int i = i0 + q * 4 + r;
        h2t_hi[m * 4096 + i] = f2bfh(v);
        float s1 = v * a1v, s2 = v * a2v;
        #pragma unroll
        for (int off = 1; off < 16; off <<= 1) {
            s1 += __shfl_xor(s1, off);
            s2 += __shfl_xor(s2, off);
        }
        if (m == 0) { fq[i] = s1; fq[4096 + i] = s2; }
    }
}

// ---------------- Fin2: out = sum(p2)/sum(z2) (f32) ---------------------------
__global__ __launch_bounds__(256)
void fin2(const float* __restrict__ pp, const float* __restrict__ zp, int nj,
          float* __restrict__ out) {
    int idx = blockIdx.x * 256 + threadIdx.x;      // 65536
    float s = 0.f;
    for (int jc = 0; jc < nj; jc++) s += pp[jc * 65536 + idx];
    float zz = 0.f;
    for (int jc = 0; jc < nj; jc++) zz += zp[jc * 4096 + (idx >> 4)];
    out[idx] = s / zz;
}

extern "C" void kernel_launch(void* const* d_in, const int* in_sizes, int n_in,
                              void* d_out, int out_size, void* d_ws, size_t ws_size,
                              hipStream_t stream) {
    const float* x   = (const float*)d_in[0];
    const int*   adj = (const int*)d_in[1];
    const float* w1  = (const float*)d_in[2];
    const float* a11 = (const float*)d_in[3];
    const float* a21 = (const float*)d_in[4];
    const float* w2  = (const float*)d_in[5];
    const float* a12 = (const float*)d_in[6];
    const float* a22 = (const float*)d_in[7];
    float* out = (float*)d_out;

    uint8_t* w = (uint8_t*)d_ws;
    unsigned long long* bm  = (unsigned long long*)(w);                       // 2 MB
    unsigned short* h1t_hi  = (unsigned short*)(w + (2u << 20));              // 2 MB
    unsigned short* h2t_hi  = (unsigned short*)(w + (4u << 20));              // 128 KB
    float*          fvals   = (float*)(w + (4u << 20) + (128u << 10));        // 128 KB
    float*          fq      = (float*)(w + (4u << 20) + (256u << 10));        // 32 KB
    unsigned short* w1h     = (unsigned short*)(w + (4u << 20) + (288u << 10)); // 128 KB
    unsigned short* w1l     = (unsigned short*)(w + (4u << 20) + (416u << 10)); // 128 KB
    unsigned short* w2h     = (unsigned short*)(w + (4u << 20) + (544u << 10)); // 8 KB
    unsigned short* w2l     = (unsigned short*)(w + (4u << 20) + (552u << 10)); // 8 KB
    unsigned short* helu_hi = (unsigned short*)(w + (4u << 20) + (560u << 10)); // 2 MB
    unsigned short* helu_lo = (unsigned short*)(w + (4u << 20) + (2608u << 10)); // 2 MB

    bool big = ws_size >= ((size_t)48 << 20);
    float* p1 = (float*)(w + (9u << 20));
    float *z1, *p2, *z2;
    if (big) {
        z1 = p1 + (size_t)8 * 4096 * 256;       // p1: 8 x 4 MB = 32 MB
        p2 = z1 + 8 * 4 * 4096;                 // z1: 8 x 64 KB
        z2 = p2 + (size_t)16 * 4096 * 16;       // p2: 16 x 256 KB = 4 MB
    } else {
        z1 = p1 + 4096 * 256;                   // p1: 4 MB
        p2 = z1 + 4 * 4096;                     // z1: 64 KB
        z2 = p2 + 4096 * 16;                    // p2: 256 KB, z2: 16 KB
    }

    if (!big) kzero<<<1108, 256, 0, stream>>>((float4*)p1);
    kpre<<<8260, 256, 0, stream>>>(adj, bm, w1, w2, w1h, w1l, w2h, w2l);
    k1_gemm<<<256, 256, 0, stream>>>(x, w1h, w1l, a11, a21, h1t_hi, fvals);
    if (big)
        attn_kernel<4, 512, false><<<dim3(32, 4, 8), 256, 0, stream>>>(
            (const unsigned char*)bm, fvals, fvals + 16384, h1t_hi, p1, z1, 256);
    else
        attn_kernel<4, 512, true><<<dim3(32, 4, 8), 256, 0, stream>>>(
            (const unsigned char*)bm, fvals, fvals + 16384, h1t_hi, p1, z1, 256);
    fin1c<<<4096, 256, 0, stream>>>(p1, z1, big ? 8 : 1, helu_hi, helu_lo);
    k3_layer2<<<64, 256, 0, stream>>>(helu_hi, helu_lo, w2h, w2l, a12, a22,
                                      h2t_hi, fq);
    if (big)
        attn_kernel<1, 256, false><<<dim3(32, 1, 16), 256, 0, stream>>>(
            (const unsigned char*)bm, fq, fq + 4096, h2t_hi, p2, z2, 16);
    else
        attn_kernel<1, 256, true><<<dim3(32, 1, 16), 256, 0, stream>>>(
            (const unsigned char*)bm, fq, fq + 4096, h2t_hi, p2, z2, 16);
    fin2<<<256, 256, 0, stream>>>(p2, z2, big ? 16 : 1, out);
}